// Round 1
// baseline (21227.235 us; speedup 1.0000x reference)
//
#include <hip/hip_runtime.h>
#include <math.h>

#define T_ 512
#define B_ 128
#define Y_ 22
#define NWG 256
#define NSLOT (T_ + 3)
#define LOG_SQRT_2PI 0.91893853320467274178f

typedef float f32x4 __attribute__((ext_vector_type(4)));
typedef short bf16x8 __attribute__((ext_vector_type(8)));

#define MFMA(a, b, c) __builtin_amdgcn_mfma_f32_16x16x32_bf16(a, b, c, 0, 0, 0)

// ---------------- workspace layout (bytes) ----------------
#define OFF_WH0 0UL
#define SZ_GATE (32UL * 3 * 64 * 128 * 2)   // 1572864: [cg][g][k8][16][8] bf16
#define OFF_WX0 (OFF_WH0 + SZ_GATE)
#define SZ_WX0 (32UL * 3 * 4 * 128 * 2)     // 98304 (K padded 22->32)
#define OFF_WX1 (OFF_WX0 + SZ_WX0)
#define OFF_WH1 (OFF_WX1 + SZ_GATE)
#define OFF_WD1 (OFF_WH1 + SZ_GATE)
#define SZ_SQ (32UL * 64 * 128 * 2)         // 524288
#define OFF_WD2 (OFF_WD1 + SZ_SQ)
#define OFF_WM (OFF_WD2 + SZ_SQ)
#define SZ_HD (2UL * 64 * 128 * 2)          // 32768 (cols padded 22->32)
#define OFF_WS2 (OFF_WM + SZ_HD)
#define OFF_YBF (OFF_WS2 + SZ_HD)
#define SZ_YBF (512UL * 128 * 32 * 2)       // 4 MB
#define OFF_H0F (OFF_YBF + SZ_YBF)          // ---- zeroed region starts here
#define SZ_HF (2UL * 128 * 512 * 4)
#define OFF_H1F (OFF_H0F + SZ_HF)
#define OFF_H0B (OFF_H1F + SZ_HF)
#define SZ_HB (2UL * 128 * 512 * 2)
#define OFF_H1B (OFF_H0B + SZ_HB)
#define OFF_D1 (OFF_H1B + SZ_HB)
#define OFF_D2 (OFF_D1 + SZ_HB)
#define OFF_NLL (OFF_D2 + SZ_HB)
#define OFF_CNT (OFF_NLL + 256)
#define OFF_END (OFF_CNT + 4UL * (NSLOT + 4))

#define SMEM_BYTES 106496  // GRU1: 96KB weights + 8KB cross-wave partials

struct Params {
  const float* states;
  const float *Wd1, *bd1, *Wd2, *bd2, *Wm, *bm, *Ws, *bs;
  const float *Wx0, *Wh0, *bx0, *bh0, *Wx1, *Wh1, *bx1, *bh1;
  char* ws;
  float* out;
};

__device__ __forceinline__ unsigned short f2bf(float f) {
  unsigned x = __float_as_uint(f);
  return (unsigned short)((x + 0x7fffu + ((x >> 16) & 1u)) >> 16);
}

// ---------------- prep kernel: zero state, bf16-convert & tile weights ----------------
__device__ void prep_gate(const float* src, unsigned short* d, size_t t0, size_t nt) {
  const size_t n = 32UL * 3 * 64 * 128;  // [cg][g][k8][cl][e], src [512][1536]
  for (size_t i = t0; i < n; i += nt) {
    int e = (int)(i & 7), cl = (int)((i >> 3) & 15), k8 = (int)((i >> 7) & 63);
    int g = (int)((i >> 13) % 3), cg = (int)(i / 24576);
    int k = k8 * 8 + e, nn = g * 512 + cg * 16 + cl;
    d[i] = f2bf(src[(size_t)k * 1536 + nn]);
  }
}
__device__ void prep_sq(const float* src, unsigned short* d, size_t t0, size_t nt) {
  const size_t n = 32UL * 64 * 128;  // [cg][k8][cl][e], src [512][512]
  for (size_t i = t0; i < n; i += nt) {
    int e = (int)(i & 7), cl = (int)((i >> 3) & 15), k8 = (int)((i >> 7) & 63);
    int cg = (int)(i >> 13);
    int k = k8 * 8 + e, nn = cg * 16 + cl;
    d[i] = f2bf(src[(size_t)k * 512 + nn]);
  }
}
__device__ void prep_head(const float* src, unsigned short* d, size_t t0, size_t nt) {
  const size_t n = 2UL * 64 * 128;  // [hc][k8][cl][e], src [512][22]
  for (size_t i = t0; i < n; i += nt) {
    int e = (int)(i & 7), cl = (int)((i >> 3) & 15), k8 = (int)((i >> 7) & 63);
    int hc = (int)(i >> 13);
    int k = k8 * 8 + e, nn = hc * 16 + cl;
    d[i] = (nn < Y_) ? f2bf(src[(size_t)k * Y_ + nn]) : (unsigned short)0;
  }
}

extern "C" __global__ void rnn_prep(Params p) {
  char* ws = p.ws;
  size_t t0 = (size_t)blockIdx.x * blockDim.x + threadIdx.x;
  size_t nt = (size_t)gridDim.x * blockDim.x;
  // zero all mutable state (h rings, d rings, nll, barrier counters)
  {
    unsigned* z = (unsigned*)(ws + OFF_H0F);
    size_t n = (OFF_END - OFF_H0F) / 4;
    for (size_t i = t0; i < n; i += nt) z[i] = 0u;
  }
  // y -> bf16, K padded to 32
  {
    unsigned short* yb = (unsigned short*)(ws + OFF_YBF);
    size_t n = (size_t)T_ * B_ * 32;
    for (size_t i = t0; i < n; i += nt) {
      int k = (int)(i & 31);
      size_t tb = i >> 5;
      float v = (k < Y_) ? p.states[tb * Y_ + k] : 0.f;
      yb[i] = f2bf(v);
    }
  }
  prep_gate(p.Wh0, (unsigned short*)(ws + OFF_WH0), t0, nt);
  prep_gate(p.Wx1, (unsigned short*)(ws + OFF_WX1), t0, nt);
  prep_gate(p.Wh1, (unsigned short*)(ws + OFF_WH1), t0, nt);
  {  // Wx0 [22][1536] -> [cg][g][k8(4)][16][8], zero-padded K
    unsigned short* d = (unsigned short*)(ws + OFF_WX0);
    size_t n = 32UL * 3 * 4 * 128;
    for (size_t i = t0; i < n; i += nt) {
      int e = (int)(i & 7), cl = (int)((i >> 3) & 15), k8 = (int)((i >> 7) & 3);
      int g = (int)((i >> 9) % 3), cg = (int)(i / 1536);
      int k = k8 * 8 + e, nn = g * 512 + cg * 16 + cl;
      d[i] = (k < Y_) ? f2bf(p.Wx0[(size_t)k * 1536 + nn]) : (unsigned short)0;
    }
  }
  prep_sq(p.Wd1, (unsigned short*)(ws + OFF_WD1), t0, nt);
  prep_sq(p.Wd2, (unsigned short*)(ws + OFF_WD2), t0, nt);
  prep_head(p.Wm, (unsigned short*)(ws + OFF_WM), t0, nt);
  prep_head(p.Ws, (unsigned short*)(ws + OFF_WS2), t0, nt);
}

// ---------------- main persistent kernel ----------------
__device__ __forceinline__ void ldscpy(char* dst, const char* src, int bytes) {
  f32x4* d = (f32x4*)dst;
  const f32x4* s = (const f32x4*)src;
  int n = bytes >> 4;
  for (int i = threadIdx.x; i < n; i += 256) d[i] = s[i];
}

__device__ __forceinline__ void gbar(unsigned* cnt, int s, unsigned n) {
  __syncthreads();  // drains vmcnt: all block stores reach (local) L2
  if (threadIdx.x == 0) {
    __threadfence();  // wb L2 -> device coherence point (release)
    atomicAdd(&cnt[s], 1u);
    while (__hip_atomic_load(&cnt[s], __ATOMIC_ACQUIRE, __HIP_MEMORY_SCOPE_AGENT) < n)
      __builtin_amdgcn_s_sleep(2);
    __threadfence();  // inv L1/L2 (acquire) for the whole CU/XCD
  }
  __syncthreads();
}

extern "C" __global__ void __launch_bounds__(256) rnn_main(Params p) {
  extern __shared__ char smem[];
  char* ws = p.ws;
  unsigned* cnt = (unsigned*)(ws + OFF_CNT);
  float* h0f = (float*)(ws + OFF_H0F);
  float* h1f = (float*)(ws + OFF_H1F);
  unsigned short* h0b = (unsigned short*)(ws + OFF_H0B);
  unsigned short* h1b = (unsigned short*)(ws + OFF_H1B);
  unsigned short* d1b = (unsigned short*)(ws + OFF_D1);
  unsigned short* d2b = (unsigned short*)(ws + OFF_D2);
  const unsigned short* ybf = (const unsigned short*)(ws + OFF_YBF);

  const int bid = blockIdx.x, tid = threadIdx.x;
  const int wv = tid >> 6, lane = tid & 63;
  const int l16 = lane & 15, lq = lane >> 4;
  const unsigned nwg = gridDim.x;

  // ---- prologue: stage this WG's weight columns into LDS (once) ----
  if (bid < 128) {  // GRU1
    int cg = bid & 31;
    ldscpy(smem, ws + OFF_WX1 + (size_t)cg * 49152, 49152);
    ldscpy(smem + 49152, ws + OFF_WH1 + (size_t)cg * 49152, 49152);
  } else if (bid < 192) {  // GRU0
    int cg = (bid - 128) & 31;
    ldscpy(smem, ws + OFF_WH0 + (size_t)cg * 49152, 49152);
    ldscpy(smem + 49152, ws + OFF_WX0 + (size_t)cg * 3072, 3072);
  } else if (bid < 224) {  // D1 (+heads on first 8)
    int cg = bid - 192;
    ldscpy(smem, ws + OFF_WD1 + (size_t)cg * 16384, 16384);
    if (cg < 8) {
      int hc = cg & 1;
      ldscpy(smem + 16384, ws + OFF_WM + (size_t)hc * 16384, 16384);
      ldscpy(smem + 32768, ws + OFF_WS2 + (size_t)hc * 16384, 16384);
    }
  } else {  // D2
    int cg = bid - 224;
    ldscpy(smem, ws + OFF_WD2 + (size_t)cg * 16384, 16384);
  }
  __syncthreads();

  for (int s = 0; s < NSLOT; ++s) {
    if (bid < 128) {
      // ================= GRU1: h1(s-1) = GRUcell(h0(s-1), h1(s-2)) =================
      const int ms = bid >> 5, cg = bid & 31;
      const int mt = wv >> 1, kh = wv & 1;  // 2 waves per 16x16 M-tile, K split in half
      float* part = (float*)(smem + 98304);
      const bool act = (s >= 1 && s <= T_);
      const int m0 = 32 * ms + 16 * mt;
      const int j = cg * 16 + l16;
      f32x4 zz = {0.f, 0.f, 0.f, 0.f};
      f32x4 aR = zz, aZ = zz, aXN = zz, aHN = zz;
      if (act) {
        if (kh == 0) {
          float bR = p.bx1[j] + p.bh1[j];
          float bZ = p.bx1[512 + j] + p.bh1[512 + j];
          float bN = p.bx1[1024 + j], bH = p.bh1[1024 + j];
          aR = f32x4{bR, bR, bR, bR};
          aZ = f32x4{bZ, bZ, bZ, bZ};
          aXN = f32x4{bN, bN, bN, bN};
          aHN = f32x4{bH, bH, bH, bH};
        }
        const unsigned short* A1 = h0b + ((s - 1) & 1) * 65536;
        const unsigned short* A2 = h1b + ((s - 2) & 1) * 65536;
        const unsigned short* wx = (const unsigned short*)smem;
        const unsigned short* wh = wx + 24576;
        const int ab = (m0 + l16) * 512 + kh * 256 + 8 * lq;
#pragma unroll
        for (int kk = 0; kk < 8; ++kk) {
          bf16x8 a1 = *(const bf16x8*)(A1 + ab + kk * 32);
          int bo = ((kh * 8 + kk) * 4 + lq) * 128 + l16 * 8;
          aR = MFMA(a1, *(const bf16x8*)(wx + bo), aR);
          aZ = MFMA(a1, *(const bf16x8*)(wx + 8192 + bo), aZ);
          aXN = MFMA(a1, *(const bf16x8*)(wx + 16384 + bo), aXN);
          bf16x8 a2 = *(const bf16x8*)(A2 + ab + kk * 32);
          aR = MFMA(a2, *(const bf16x8*)(wh + bo), aR);
          aZ = MFMA(a2, *(const bf16x8*)(wh + 8192 + bo), aZ);
          aHN = MFMA(a2, *(const bf16x8*)(wh + 16384 + bo), aHN);
        }
        if (kh == 1) {
          float* q = part + (mt * 64 + lane) * 16;
          *(f32x4*)(q + 0) = aR;
          *(f32x4*)(q + 4) = aZ;
          *(f32x4*)(q + 8) = aXN;
          *(f32x4*)(q + 12) = aHN;
        }
      }
      __syncthreads();
      if (act && kh == 0) {
        const float* q = part + (mt * 64 + lane) * 16;
        aR += *(const f32x4*)(q + 0);
        aZ += *(const f32x4*)(q + 4);
        aXN += *(const f32x4*)(q + 8);
        aHN += *(const f32x4*)(q + 12);
        const float* hp = h1f + ((s - 2) & 1) * 65536;
        float* hfn = h1f + ((s - 1) & 1) * 65536;
        unsigned short* hbn = h1b + ((s - 1) & 1) * 65536;
#pragma unroll
        for (int i = 0; i < 4; ++i) {
          int row = m0 + lq * 4 + i;
          float r = 1.f / (1.f + __expf(-aR[i]));
          float z = 1.f / (1.f + __expf(-aZ[i]));
          float n = tanhf(aXN[i] + r * aHN[i]);
          float hv = (1.f - z) * n + z * hp[row * 512 + j];
          hfn[row * 512 + j] = hv;
          hbn[row * 512 + j] = f2bf(hv);
        }
      }
    } else if (bid < 192) {
      // ================= GRU0: h0(s) = GRUcell(y_s, h0(s-1)) =================
      const int idx = bid - 128, ms = idx >> 5, cg = idx & 31;
      if (s < T_) {
        const unsigned short* A = h0b + ((s - 1) & 1) * 65536;
        const unsigned short* yb = ybf + (size_t)s * (128 * 32);
        const unsigned short* wh = (const unsigned short*)smem;
        const unsigned short* wx = wh + 24576;
        const int m0 = 64 * ms + 16 * wv;
        const int j = cg * 16 + l16;
        float bR = p.bx0[j] + p.bh0[j];
        float bZ = p.bx0[512 + j] + p.bh0[512 + j];
        float bN = p.bx0[1024 + j], bH = p.bh0[1024 + j];
        f32x4 aR = {bR, bR, bR, bR}, aZ = {bZ, bZ, bZ, bZ};
        f32x4 aN = {bN, bN, bN, bN}, aH = {bH, bH, bH, bH};
        {  // x-part, K=32 (padded from 22)
          bf16x8 a = *(const bf16x8*)(yb + (m0 + l16) * 32 + 8 * lq);
          int bo = lq * 128 + l16 * 8;
          aR = MFMA(a, *(const bf16x8*)(wx + bo), aR);
          aZ = MFMA(a, *(const bf16x8*)(wx + 512 + bo), aZ);
          aN = MFMA(a, *(const bf16x8*)(wx + 1024 + bo), aN);
        }
        const int ab = (m0 + l16) * 512 + 8 * lq;
#pragma unroll
        for (int kk = 0; kk < 16; ++kk) {
          bf16x8 a = *(const bf16x8*)(A + ab + kk * 32);
          int bo = (kk * 4 + lq) * 128 + l16 * 8;
          aR = MFMA(a, *(const bf16x8*)(wh + bo), aR);
          aZ = MFMA(a, *(const bf16x8*)(wh + 8192 + bo), aZ);
          aH = MFMA(a, *(const bf16x8*)(wh + 16384 + bo), aH);
        }
        const float* hp = h0f + ((s - 1) & 1) * 65536;
        float* hfn = h0f + (s & 1) * 65536;
        unsigned short* hbn = h0b + (s & 1) * 65536;
#pragma unroll
        for (int i = 0; i < 4; ++i) {
          int row = m0 + lq * 4 + i;
          float r = 1.f / (1.f + __expf(-aR[i]));
          float z = 1.f / (1.f + __expf(-aZ[i]));
          float n = tanhf(aN[i] + r * aH[i]);
          float hv = (1.f - z) * n + z * hp[row * 512 + j];
          hfn[row * 512 + j] = hv;
          hbn[row * 512 + j] = f2bf(hv);
        }
      }
    } else if (bid < 224) {
      // ================= D1: d1(s-1) = relu(h1(s-2) @ Wd1 + bd1)  (+ heads) =================
      const int cg = bid - 192;
      if (s >= 1 && s <= T_) {
        const unsigned short* A = h1b + ((s - 2) & 1) * 65536;
        unsigned short* dst = d1b + ((s - 1) & 1) * 65536;
        const unsigned short* wd = (const unsigned short*)smem;
        const int j = cg * 16 + l16;
        float bv = p.bd1[j];
#pragma unroll
        for (int half = 0; half < 2; ++half) {
          int m0 = (wv * 2 + half) * 16;
          f32x4 acc = {bv, bv, bv, bv};
          int ab = (m0 + l16) * 512 + 8 * lq;
#pragma unroll
          for (int kk = 0; kk < 16; ++kk) {
            bf16x8 a = *(const bf16x8*)(A + ab + kk * 32);
            int bo = (kk * 4 + lq) * 128 + l16 * 8;
            acc = MFMA(a, *(const bf16x8*)(wd + bo), acc);
          }
#pragma unroll
          for (int i = 0; i < 4; ++i) {
            int row = m0 + lq * 4 + i;
            float v = acc[i];
            dst[row * 512 + j] = f2bf(v > 0.f ? v : 0.f);
          }
        }
      }
      // heads + NLL for tau = s-3 (8 WGs, waves 0..1)
      if (cg < 8 && wv < 2 && s >= 3) {
        const int tau = s - 3;
        const int ms = cg >> 1, hc = cg & 1;
        const unsigned short* A = d2b + ((s - 3) & 1) * 65536;
        const unsigned short* wm = (const unsigned short*)(smem + 16384);
        const unsigned short* wst = (const unsigned short*)(smem + 32768);
        const int m0 = 32 * ms + 16 * wv;
        const int col = hc * 16 + l16;
        float bmv = (col < Y_) ? p.bm[col] : 0.f;
        float bsv = (col < Y_) ? p.bs[col] : 0.f;
        f32x4 aM = {bmv, bmv, bmv, bmv}, aS = {bsv, bsv, bsv, bsv};
        const int ab = (m0 + l16) * 512 + 8 * lq;
#pragma unroll
        for (int kk = 0; kk < 16; ++kk) {
          bf16x8 a = *(const bf16x8*)(A + ab + kk * 32);
          int bo = (kk * 4 + lq) * 128 + l16 * 8;
          aM = MFMA(a, *(const bf16x8*)(wm + bo), aM);
          aS = MFMA(a, *(const bf16x8*)(wst + bo), aS);
        }
        float lsum = 0.f;
        if (col < Y_) {
#pragma unroll
          for (int i = 0; i < 4; ++i) {
            int row = m0 + lq * 4 + i;
            float sp = aS[i];
            float sd = (sp > 20.f) ? sp : log1pf(__expf(sp));
            float yv = p.states[((size_t)tau * B_ + row) * Y_ + col];
            float tt = (yv - aM[i]) / sd;
            lsum += 0.5f * tt * tt + __logf(sd) + LOG_SQRT_2PI;
          }
        }
#pragma unroll
        for (int off = 32; off > 0; off >>= 1) lsum += __shfl_down(lsum, off);
        if (lane == 0) atomicAdd((float*)(ws + OFF_NLL), lsum);
      }
    } else {
      // ================= D2: d2(s-2) = relu(d1(s-2) @ Wd2 + bd2) =================
      const int cg = bid - 224;
      if (s >= 2 && s <= T_ + 1) {
        const unsigned short* A = d1b + ((s - 2) & 1) * 65536;
        unsigned short* dst = d2b + ((s - 2) & 1) * 65536;
        const unsigned short* wd = (const unsigned short*)smem;
        const int j = cg * 16 + l16;
        float bv = p.bd2[j];
#pragma unroll
        for (int half = 0; half < 2; ++half) {
          int m0 = (wv * 2 + half) * 16;
          f32x4 acc = {bv, bv, bv, bv};
          int ab = (m0 + l16) * 512 + 8 * lq;
#pragma unroll
          for (int kk = 0; kk < 16; ++kk) {
            bf16x8 a = *(const bf16x8*)(A + ab + kk * 32);
            int bo = (kk * 4 + lq) * 128 + l16 * 8;
            acc = MFMA(a, *(const bf16x8*)(wd + bo), acc);
          }
#pragma unroll
          for (int i = 0; i < 4; ++i) {
            int row = m0 + lq * 4 + i;
            float v = acc[i];
            dst[row * 512 + j] = f2bf(v > 0.f ? v : 0.f);
          }
        }
      }
    }
    gbar(cnt, s, nwg);
  }

  if (bid == 0 && tid == 0) p.out[0] = *(const float*)(ws + OFF_NLL);
}

// ---------------- host launcher ----------------
extern "C" void kernel_launch(void* const* d_in, const int* in_sizes, int n_in,
                              void* d_out, int out_size, void* d_ws, size_t ws_size,
                              hipStream_t stream) {
  if (ws_size < OFF_END) return;  // insufficient scratch -> visible failure
  Params p;
  p.states = (const float*)d_in[0];
  p.Wd1 = (const float*)d_in[1];
  p.bd1 = (const float*)d_in[2];
  p.Wd2 = (const float*)d_in[3];
  p.bd2 = (const float*)d_in[4];
  p.Wm = (const float*)d_in[5];
  p.bm = (const float*)d_in[6];
  p.Ws = (const float*)d_in[7];
  p.bs = (const float*)d_in[8];
  p.Wx0 = (const float*)d_in[9];
  p.Wh0 = (const float*)d_in[10];
  p.bx0 = (const float*)d_in[11];
  p.bh0 = (const float*)d_in[12];
  p.Wx1 = (const float*)d_in[13];
  p.Wh1 = (const float*)d_in[14];
  p.bx1 = (const float*)d_in[15];
  p.bh1 = (const float*)d_in[16];
  p.ws = (char*)d_ws;
  p.out = (float*)d_out;

  hipLaunchKernelGGL(rnn_prep, dim3(512), dim3(256), 0, stream, p);

  hipFuncSetAttribute((const void*)rnn_main, hipFuncAttributeMaxDynamicSharedMemorySize,
                      SMEM_BYTES);
  void* args[] = {&p};
  hipLaunchCooperativeKernel((const void*)rnn_main, dim3(NWG), dim3(256), args, SMEM_BYTES,
                             stream);
}

// Round 6
// 10763.113 us; speedup vs baseline: 1.9722x; 1.9722x over previous
//
#include <hip/hip_runtime.h>
#include <math.h>

#define T_ 512
#define B_ 128
#define Y_ 22
#define NWG 256
#define NSLOT (T_ + 3)
#define LOG_SQRT_2PI 0.91893853320467274178f

typedef float f32x4 __attribute__((ext_vector_type(4)));
typedef short bf16x8 __attribute__((ext_vector_type(8)));

#define MFMA(a, b, c) __builtin_amdgcn_mfma_f32_16x16x32_bf16(a, b, c, 0, 0, 0)

// ---------------- workspace layout (bytes) ----------------
#define OFF_WH0 0UL
#define SZ_GATE (32UL * 3 * 64 * 128 * 2)   // 1572864: [cg][g][k8][16][8] bf16
#define OFF_WX0 (OFF_WH0 + SZ_GATE)
#define SZ_WX0 (32UL * 3 * 4 * 128 * 2)     // 98304 (K padded 22->32)
#define OFF_WX1 (OFF_WX0 + SZ_WX0)
#define OFF_WH1 (OFF_WX1 + SZ_GATE)
#define OFF_WD1 (OFF_WH1 + SZ_GATE)
#define SZ_SQ (32UL * 64 * 128 * 2)         // 524288
#define OFF_WD2 (OFF_WD1 + SZ_SQ)
#define OFF_WM (OFF_WD2 + SZ_SQ)
#define SZ_HD (2UL * 64 * 128 * 2)          // 32768 (cols padded 22->32)
#define OFF_WS2 (OFF_WM + SZ_HD)
#define OFF_YBF (OFF_WS2 + SZ_HD)
#define SZ_YBF (512UL * 128 * 32 * 2)       // 4 MB
#define OFF_H0B (OFF_YBF + SZ_YBF)          // ---- zeroed region starts here
#define SZ_HB (2UL * 128 * 512 * 2)
#define OFF_H1B (OFF_H0B + SZ_HB)
#define OFF_D1 (OFF_H1B + SZ_HB)
#define OFF_D2 (OFF_D1 + SZ_HB)
#define OFF_NLL (OFF_D2 + SZ_HB)
#define OFF_CNT (OFF_NLL + 256)                 // root counters: 64B stride per slot
#define OFF_SUB (OFF_CNT + 64UL * NSLOT)        // 16 groups x 2176B (544 slots x4B)
#define OFF_END (OFF_SUB + 16UL * 2176)

#define SMEM_BYTES 106496  // GRU1: 96KB weights + 8KB cross-wave partials

struct Params {
  const float* states;
  const float *Wd1, *bd1, *Wd2, *bd2, *Wm, *bm, *Ws, *bs;
  const float *Wx0, *Wh0, *bx0, *bh0, *Wx1, *Wh1, *bx1, *bh1;
  char* ws;
  float* out;
};

__device__ __forceinline__ unsigned short f2bf(float f) {
  unsigned x = __float_as_uint(f);
  return (unsigned short)((x + 0x7fffu + ((x >> 16) & 1u)) >> 16);
}

// Coherent poll: sc0sc1 load bypasses stale L1/L2, no cache invalidation cost.
__device__ __forceinline__ unsigned cpoll(const unsigned* p) {
  unsigned r;
  asm volatile("global_load_dword %0, %1, off sc0 sc1\n\ts_waitcnt vmcnt(0)"
               : "=v"(r)
               : "v"(p)
               : "memory");
  return r;
}

// ---------------- prep kernel: zero state, bf16-convert & tile weights ----------------
__device__ void prep_gate(const float* src, unsigned short* d, size_t t0, size_t nt) {
  const size_t n = 32UL * 3 * 64 * 128;  // [cg][g][k8][cl][e], src [512][1536]
  for (size_t i = t0; i < n; i += nt) {
    int e = (int)(i & 7), cl = (int)((i >> 3) & 15), k8 = (int)((i >> 7) & 63);
    int g = (int)((i >> 13) % 3), cg = (int)(i / 24576);
    int k = k8 * 8 + e, nn = g * 512 + cg * 16 + cl;
    d[i] = f2bf(src[(size_t)k * 1536 + nn]);
  }
}
__device__ void prep_sq(const float* src, unsigned short* d, size_t t0, size_t nt) {
  const size_t n = 32UL * 64 * 128;  // [cg][k8][cl][e], src [512][512]
  for (size_t i = t0; i < n; i += nt) {
    int e = (int)(i & 7), cl = (int)((i >> 3) & 15), k8 = (int)((i >> 7) & 63);
    int cg = (int)(i >> 13);
    int k = k8 * 8 + e, nn = cg * 16 + cl;
    d[i] = f2bf(src[(size_t)k * 512 + nn]);
  }
}
__device__ void prep_head(const float* src, unsigned short* d, size_t t0, size_t nt) {
  const size_t n = 2UL * 64 * 128;  // [hc][k8][cl][e], src [512][22]
  for (size_t i = t0; i < n; i += nt) {
    int e = (int)(i & 7), cl = (int)((i >> 3) & 15), k8 = (int)((i >> 7) & 63);
    int hc = (int)(i >> 13);
    int k = k8 * 8 + e, nn = hc * 16 + cl;
    d[i] = (nn < Y_) ? f2bf(src[(size_t)k * Y_ + nn]) : (unsigned short)0;
  }
}

extern "C" __global__ void rnn_prep(Params p) {
  char* ws = p.ws;
  size_t t0 = (size_t)blockIdx.x * blockDim.x + threadIdx.x;
  size_t nt = (size_t)gridDim.x * blockDim.x;
  // zero all mutable state (h/d rings, nll, barrier counters)
  {
    unsigned* z = (unsigned*)(ws + OFF_H0B);
    size_t n = (OFF_END - OFF_H0B) / 4;
    for (size_t i = t0; i < n; i += nt) z[i] = 0u;
  }
  // y -> bf16, K padded to 32
  {
    unsigned short* yb = (unsigned short*)(ws + OFF_YBF);
    size_t n = (size_t)T_ * B_ * 32;
    for (size_t i = t0; i < n; i += nt) {
      int k = (int)(i & 31);
      size_t tb = i >> 5;
      float v = (k < Y_) ? p.states[tb * Y_ + k] : 0.f;
      yb[i] = f2bf(v);
    }
  }
  prep_gate(p.Wh0, (unsigned short*)(ws + OFF_WH0), t0, nt);
  prep_gate(p.Wx1, (unsigned short*)(ws + OFF_WX1), t0, nt);
  prep_gate(p.Wh1, (unsigned short*)(ws + OFF_WH1), t0, nt);
  {  // Wx0 [22][1536] -> [cg][g][k8(4)][16][8], zero-padded K
    unsigned short* d = (unsigned short*)(ws + OFF_WX0);
    size_t n = 32UL * 3 * 4 * 128;
    for (size_t i = t0; i < n; i += nt) {
      int e = (int)(i & 7), cl = (int)((i >> 3) & 15), k8 = (int)((i >> 7) & 3);
      int g = (int)((i >> 9) % 3), cg = (int)(i / 1536);
      int k = k8 * 8 + e, nn = g * 512 + cg * 16 + cl;
      d[i] = (k < Y_) ? f2bf(p.Wx0[(size_t)k * 1536 + nn]) : (unsigned short)0;
    }
  }
  prep_sq(p.Wd1, (unsigned short*)(ws + OFF_WD1), t0, nt);
  prep_sq(p.Wd2, (unsigned short*)(ws + OFF_WD2), t0, nt);
  prep_head(p.Wm, (unsigned short*)(ws + OFF_WM), t0, nt);
  prep_head(p.Ws, (unsigned short*)(ws + OFF_WS2), t0, nt);
}

// ---------------- main persistent kernel ----------------
__device__ __forceinline__ void ldscpy(char* dst, const char* src, int bytes) {
  f32x4* d = (f32x4*)dst;
  const f32x4* s = (const f32x4*)src;
  int n = bytes >> 4;
  for (int i = threadIdx.x; i < n; i += 256) d[i] = s[i];
}

// Proven round-0 protocol (plain cached data + threadfence release/acquire),
// but: 2-level tree (16x16) to cut atomic serialization, and relaxed coherent
// polls (sc0sc1 loads, NO buffer_inv per iteration). Exactly ONE acquire fence
// after the spin exits.
__device__ __forceinline__ void gbar(char* ws, int s, int bid) {
  __syncthreads();  // compiler drains vmcnt/lgkmcnt before s_barrier
  if (threadIdx.x == 0) {
    __threadfence();  // release: write back this XCD's L2 to coherence point
    const int g = bid & 15;
    unsigned* sc = (unsigned*)(ws + OFF_SUB) + (size_t)g * 544 + s;
    unsigned* rc = (unsigned*)(ws + OFF_CNT) + (size_t)s * 16;
    atomicAdd(sc, 1u);
    if (bid < 16) {
      while (cpoll(sc) < 16u) __builtin_amdgcn_s_sleep(1);
      atomicAdd(rc, 1u);
    }
    while (cpoll(rc) < 16u) __builtin_amdgcn_s_sleep(1);
    __threadfence();  // acquire: invalidate L1/L2 so plain loads see fresh data
  }
  __syncthreads();
}

extern "C" __global__ void __launch_bounds__(256) rnn_main(Params p) {
  extern __shared__ char smem[];
  char* ws = p.ws;
  unsigned short* h0b = (unsigned short*)(ws + OFF_H0B);
  unsigned short* h1b = (unsigned short*)(ws + OFF_H1B);
  unsigned short* d1b = (unsigned short*)(ws + OFF_D1);
  unsigned short* d2b = (unsigned short*)(ws + OFF_D2);
  const unsigned short* ybf = (const unsigned short*)(ws + OFF_YBF);

  const int bid = blockIdx.x, tid = threadIdx.x;
  const int wv = tid >> 6, lane = tid & 63;
  const int l16 = lane & 15, lq = lane >> 4;

  // ---- prologue: stage this WG's weight columns into LDS (once) ----
  if (bid < 128) {  // GRU1
    int cg = bid & 31;
    ldscpy(smem, ws + OFF_WX1 + (size_t)cg * 49152, 49152);
    ldscpy(smem + 49152, ws + OFF_WH1 + (size_t)cg * 49152, 49152);
  } else if (bid < 192) {  // GRU0
    int cg = (bid - 128) & 31;
    ldscpy(smem, ws + OFF_WH0 + (size_t)cg * 49152, 49152);
    ldscpy(smem + 49152, ws + OFF_WX0 + (size_t)cg * 3072, 3072);
  } else if (bid < 224) {  // D1 (+heads on first 8)
    int cg = bid - 192;
    ldscpy(smem, ws + OFF_WD1 + (size_t)cg * 16384, 16384);
    if (cg < 8) {
      int hc = cg & 1;
      ldscpy(smem + 16384, ws + OFF_WM + (size_t)hc * 16384, 16384);
      ldscpy(smem + 32768, ws + OFF_WS2 + (size_t)hc * 16384, 16384);
    }
  } else {  // D2
    int cg = bid - 224;
    ldscpy(smem, ws + OFF_WD2 + (size_t)cg * 16384, 16384);
  }
  __syncthreads();

  // ---- hoisted per-thread constants + register-resident fp32 h state ----
  // (producer lane == consumer lane across slots, so the fp32 carry never
  //  crosses WG/coherence boundaries)
  f32x4 hreg = {0.f, 0.f, 0.f, 0.f};
  float cA = 0.f, cB = 0.f, cC = 0.f, cD = 0.f, cM = 0.f, cS = 0.f;
  if (bid < 128) {
    const int cg = bid & 31, kh = wv & 1;
    const int j = cg * 16 + l16;
    if (kh == 0) {
      cA = p.bx1[j] + p.bh1[j];
      cB = p.bx1[512 + j] + p.bh1[512 + j];
      cC = p.bx1[1024 + j];
      cD = p.bh1[1024 + j];
    }
  } else if (bid < 192) {
    const int cg = (bid - 128) & 31;
    const int j = cg * 16 + l16;
    cA = p.bx0[j] + p.bh0[j];
    cB = p.bx0[512 + j] + p.bh0[512 + j];
    cC = p.bx0[1024 + j];
    cD = p.bh0[1024 + j];
  } else if (bid < 224) {
    const int cg = bid - 192;
    cA = p.bd1[cg * 16 + l16];
    if (cg < 8 && wv < 2) {
      const int col = (cg & 1) * 16 + l16;
      cM = (col < Y_) ? p.bm[col] : 0.f;
      cS = (col < Y_) ? p.bs[col] : 0.f;
    }
  } else {
    cA = p.bd2[(bid - 224) * 16 + l16];
  }

  for (int s = 0; s < NSLOT; ++s) {
    if (bid < 128) {
      // ========== GRU1: h1(s-1) = GRUcell(h0(s-1), h1(s-2)) ==========
      const int ms = bid >> 5;
      const int mt = wv >> 1, kh = wv & 1;  // 2 waves per 16x16 M-tile, K halved
      float* part = (float*)(smem + 98304);
      const bool act = (s >= 1 && s <= T_);
      const int m0 = 32 * ms + 16 * mt;
      const int j = (bid & 31) * 16 + l16;
      f32x4 aR = {0.f, 0.f, 0.f, 0.f}, aZ = aR, aXN = aR, aHN = aR;
      if (act) {
        if (kh == 0) {
          aR = f32x4{cA, cA, cA, cA};
          aZ = f32x4{cB, cB, cB, cB};
          aXN = f32x4{cC, cC, cC, cC};
          aHN = f32x4{cD, cD, cD, cD};
        }
        const unsigned short* A1 = h0b + ((s - 1) & 1) * 65536;
        const unsigned short* A2 = h1b + ((s - 2) & 1) * 65536;
        const unsigned short* wx = (const unsigned short*)smem;
        const unsigned short* wh = wx + 24576;
        const int ab = (m0 + l16) * 512 + kh * 256 + 8 * lq;
#pragma unroll
        for (int kk = 0; kk < 8; ++kk) {
          bf16x8 a1 = *(const bf16x8*)(A1 + ab + kk * 32);
          int bo = ((kh * 8 + kk) * 4 + lq) * 128 + l16 * 8;
          aR = MFMA(a1, *(const bf16x8*)(wx + bo), aR);
          aZ = MFMA(a1, *(const bf16x8*)(wx + 8192 + bo), aZ);
          aXN = MFMA(a1, *(const bf16x8*)(wx + 16384 + bo), aXN);
          bf16x8 a2 = *(const bf16x8*)(A2 + ab + kk * 32);
          aR = MFMA(a2, *(const bf16x8*)(wh + bo), aR);
          aZ = MFMA(a2, *(const bf16x8*)(wh + 8192 + bo), aZ);
          aHN = MFMA(a2, *(const bf16x8*)(wh + 16384 + bo), aHN);
        }
        if (kh == 1) {
          float* q = part + (mt * 64 + lane) * 16;
          *(f32x4*)(q + 0) = aR;
          *(f32x4*)(q + 4) = aZ;
          *(f32x4*)(q + 8) = aXN;
          *(f32x4*)(q + 12) = aHN;
        }
      }
      __syncthreads();
      if (act && kh == 0) {
        const float* q = part + (mt * 64 + lane) * 16;
        aR += *(const f32x4*)(q + 0);
        aZ += *(const f32x4*)(q + 4);
        aXN += *(const f32x4*)(q + 8);
        aHN += *(const f32x4*)(q + 12);
        unsigned short* hbn = h1b + ((s - 1) & 1) * 65536;
#pragma unroll
        for (int i = 0; i < 4; ++i) {
          int row = m0 + lq * 4 + i;
          float r = 1.f / (1.f + __expf(-aR[i]));
          float z = 1.f / (1.f + __expf(-aZ[i]));
          float n = tanhf(aXN[i] + r * aHN[i]);
          float hv = (1.f - z) * n + z * hreg[i];
          hreg[i] = hv;
          hbn[row * 512 + j] = f2bf(hv);
        }
      }
    } else if (bid < 192) {
      // ========== GRU0: h0(s) = GRUcell(y_s, h0(s-1)) ==========
      const int idx = bid - 128, ms = idx >> 5, cg = idx & 31;
      if (s < T_) {
        const unsigned short* A = h0b + ((s - 1) & 1) * 65536;
        const unsigned short* yb = ybf + (size_t)s * (128 * 32);
        const unsigned short* wh = (const unsigned short*)smem;
        const unsigned short* wx = wh + 24576;
        const int m0 = 64 * ms + 16 * wv;
        const int j = cg * 16 + l16;
        f32x4 aR = {cA, cA, cA, cA}, aZ = {cB, cB, cB, cB};
        f32x4 aN = {cC, cC, cC, cC}, aH = {cD, cD, cD, cD};
        {  // x-part, K=32 (padded from 22)
          bf16x8 a = *(const bf16x8*)(yb + (m0 + l16) * 32 + 8 * lq);
          int bo = lq * 128 + l16 * 8;
          aR = MFMA(a, *(const bf16x8*)(wx + bo), aR);
          aZ = MFMA(a, *(const bf16x8*)(wx + 512 + bo), aZ);
          aN = MFMA(a, *(const bf16x8*)(wx + 1024 + bo), aN);
        }
        const int ab = (m0 + l16) * 512 + 8 * lq;
#pragma unroll
        for (int kk = 0; kk < 16; ++kk) {
          bf16x8 a = *(const bf16x8*)(A + ab + kk * 32);
          int bo = (kk * 4 + lq) * 128 + l16 * 8;
          aR = MFMA(a, *(const bf16x8*)(wh + bo), aR);
          aZ = MFMA(a, *(const bf16x8*)(wh + 8192 + bo), aZ);
          aH = MFMA(a, *(const bf16x8*)(wh + 16384 + bo), aH);
        }
        unsigned short* hbn = h0b + (s & 1) * 65536;
#pragma unroll
        for (int i = 0; i < 4; ++i) {
          int row = m0 + lq * 4 + i;
          float r = 1.f / (1.f + __expf(-aR[i]));
          float z = 1.f / (1.f + __expf(-aZ[i]));
          float n = tanhf(aN[i] + r * aH[i]);
          float hv = (1.f - z) * n + z * hreg[i];
          hreg[i] = hv;
          hbn[row * 512 + j] = f2bf(hv);
        }
      }
    } else if (bid < 224) {
      // ========== D1: d1(s-1) = relu(h1(s-2) @ Wd1 + bd1)  (+ heads/NLL) ==========
      const int cg = bid - 192;
      if (s >= 1 && s <= T_) {
        const unsigned short* A = h1b + ((s - 2) & 1) * 65536;
        unsigned short* dst = d1b + ((s - 1) & 1) * 65536;
        const unsigned short* wd = (const unsigned short*)smem;
        const int j = cg * 16 + l16;
#pragma unroll
        for (int half = 0; half < 2; ++half) {
          int m0 = (wv * 2 + half) * 16;
          f32x4 acc = {cA, cA, cA, cA};
          int ab = (m0 + l16) * 512 + 8 * lq;
#pragma unroll
          for (int kk = 0; kk < 16; ++kk) {
            bf16x8 a = *(const bf16x8*)(A + ab + kk * 32);
            int bo = (kk * 4 + lq) * 128 + l16 * 8;
            acc = MFMA(a, *(const bf16x8*)(wd + bo), acc);
          }
#pragma unroll
          for (int i = 0; i < 4; ++i) {
            int row = m0 + lq * 4 + i;
            float v = acc[i];
            dst[row * 512 + j] = f2bf(v > 0.f ? v : 0.f);
          }
        }
      }
      // heads + NLL for tau = s-3 (8 WGs, waves 0..1)
      if (cg < 8 && wv < 2 && s >= 3) {
        const int tau = s - 3;
        const int ms = cg >> 1, hc = cg & 1;
        const unsigned short* A = d2b + ((s - 3) & 1) * 65536;
        const unsigned short* wm = (const unsigned short*)(smem + 16384);
        const unsigned short* wst = (const unsigned short*)(smem + 32768);
        const int m0 = 32 * ms + 16 * wv;
        const int col = hc * 16 + l16;
        f32x4 aM = {cM, cM, cM, cM}, aS = {cS, cS, cS, cS};
        const int ab = (m0 + l16) * 512 + 8 * lq;
#pragma unroll
        for (int kk = 0; kk < 16; ++kk) {
          bf16x8 a = *(const bf16x8*)(A + ab + kk * 32);
          int bo = (kk * 4 + lq) * 128 + l16 * 8;
          aM = MFMA(a, *(const bf16x8*)(wm + bo), aM);
          aS = MFMA(a, *(const bf16x8*)(wst + bo), aS);
        }
        float lsum = 0.f;
        if (col < Y_) {
#pragma unroll
          for (int i = 0; i < 4; ++i) {
            int row = m0 + lq * 4 + i;
            float sp = aS[i];
            float sd = (sp > 20.f) ? sp : log1pf(__expf(sp));
            float yv = p.states[((size_t)tau * B_ + row) * Y_ + col];
            float tt = (yv - aM[i]) / sd;
            lsum += 0.5f * tt * tt + __logf(sd) + LOG_SQRT_2PI;
          }
        }
#pragma unroll
        for (int off = 32; off > 0; off >>= 1) lsum += __shfl_down(lsum, off);
        if (lane == 0) atomicAdd((float*)(ws + OFF_NLL), lsum);
      }
    } else {
      // ========== D2: d2(s-2) = relu(d1(s-2) @ Wd2 + bd2) ==========
      const int cg = bid - 224;
      if (s >= 2 && s <= T_ + 1) {
        const unsigned short* A = d1b + ((s - 2) & 1) * 65536;
        unsigned short* dst = d2b + ((s - 2) & 1) * 65536;
        const unsigned short* wd = (const unsigned short*)smem;
        const int j = cg * 16 + l16;
#pragma unroll
        for (int half = 0; half < 2; ++half) {
          int m0 = (wv * 2 + half) * 16;
          f32x4 acc = {cA, cA, cA, cA};
          int ab = (m0 + l16) * 512 + 8 * lq;
#pragma unroll
          for (int kk = 0; kk < 16; ++kk) {
            bf16x8 a = *(const bf16x8*)(A + ab + kk * 32);
            int bo = (kk * 4 + lq) * 128 + l16 * 8;
            acc = MFMA(a, *(const bf16x8*)(wd + bo), acc);
          }
#pragma unroll
          for (int i = 0; i < 4; ++i) {
            int row = m0 + lq * 4 + i;
            float v = acc[i];
            dst[row * 512 + j] = f2bf(v > 0.f ? v : 0.f);
          }
        }
      }
    }
    gbar(ws, s, bid);
  }

  // last gbar's acquire fence (tid0) already invalidated this XCD's caches
  if (bid == 0 && tid == 0) p.out[0] = *(const float*)(ws + OFF_NLL);
}

// ---------------- host launcher ----------------
extern "C" void kernel_launch(void* const* d_in, const int* in_sizes, int n_in,
                              void* d_out, int out_size, void* d_ws, size_t ws_size,
                              hipStream_t stream) {
  if (ws_size < OFF_END) return;  // insufficient scratch -> visible failure
  Params p;
  p.states = (const float*)d_in[0];
  p.Wd1 = (const float*)d_in[1];
  p.bd1 = (const float*)d_in[2];
  p.Wd2 = (const float*)d_in[3];
  p.bd2 = (const float*)d_in[4];
  p.Wm = (const float*)d_in[5];
  p.bm = (const float*)d_in[6];
  p.Ws = (const float*)d_in[7];
  p.bs = (const float*)d_in[8];
  p.Wx0 = (const float*)d_in[9];
  p.Wh0 = (const float*)d_in[10];
  p.bx0 = (const float*)d_in[11];
  p.bh0 = (const float*)d_in[12];
  p.Wx1 = (const float*)d_in[13];
  p.Wh1 = (const float*)d_in[14];
  p.bx1 = (const float*)d_in[15];
  p.bh1 = (const float*)d_in[16];
  p.ws = (char*)d_ws;
  p.out = (float*)d_out;

  hipLaunchKernelGGL(rnn_prep, dim3(512), dim3(256), 0, stream, p);

  hipFuncSetAttribute((const void*)rnn_main, hipFuncAttributeMaxDynamicSharedMemorySize,
                      SMEM_BYTES);
  void* args[] = {&p};
  hipLaunchCooperativeKernel((const void*)rnn_main, dim3(NWG), dim3(256), args, SMEM_BYTES,
                             stream);
}

// Round 7
// 5011.558 us; speedup vs baseline: 4.2357x; 2.1477x over previous
//
#include <hip/hip_runtime.h>
#include <math.h>

#define T_ 512
#define B_ 128
#define Y_ 22
#define NWG 256
#define NSLOT (T_ + 3)
#define LOG_SQRT_2PI 0.91893853320467274178f

typedef float f32x4 __attribute__((ext_vector_type(4)));
typedef short bf16x8 __attribute__((ext_vector_type(8)));

#define MFMA(a, b, c) __builtin_amdgcn_mfma_f32_16x16x32_bf16(a, b, c, 0, 0, 0)

// ---------------- workspace layout (bytes) ----------------
#define OFF_WH0 0UL
#define SZ_GATE (32UL * 3 * 64 * 128 * 2)   // 1572864: [cg][g][k8][16][8] bf16
#define OFF_WX0 (OFF_WH0 + SZ_GATE)
#define SZ_WX0 (32UL * 3 * 4 * 128 * 2)     // 98304 (K padded 22->32)
#define OFF_WX1 (OFF_WX0 + SZ_WX0)
#define OFF_WH1 (OFF_WX1 + SZ_GATE)
#define OFF_WD1 (OFF_WH1 + SZ_GATE)
#define SZ_SQ (32UL * 64 * 128 * 2)         // 524288
#define OFF_WD2 (OFF_WD1 + SZ_SQ)
#define OFF_WM (OFF_WD2 + SZ_SQ)
#define SZ_HD (2UL * 64 * 128 * 2)          // 32768 (cols padded 22->32)
#define OFF_WS2 (OFF_WM + SZ_HD)
#define OFF_YBF (OFF_WS2 + SZ_HD)
#define SZ_YBF (512UL * 128 * 32 * 2)       // 4 MB
#define OFF_H0B (OFF_YBF + SZ_YBF)          // ---- zeroed region starts here
#define SZ_HB (2UL * 128 * 512 * 2)
#define OFF_H1B (OFF_H0B + SZ_HB)
#define OFF_D1 (OFF_H1B + SZ_HB)
#define OFF_D2 (OFF_D1 + SZ_HB)
#define OFF_NLL (OFF_D2 + SZ_HB)
#define OFF_INITC (OFF_NLL + 64)
#define OFF_XCDC (OFF_INITC + 64)               // 16 x u32 per-XCD WG counts
#define OFF_ROOT (OFF_XCDC + 64)                // NSLOT x 64B root counters
#define OFF_ARR (OFF_ROOT + 64UL * NSLOT)       // 16 XCD x NSLOT arrival counters
#define OFF_DON (OFF_ARR + 4UL * 16 * NSLOT)    // 16 XCD x NSLOT done flags
#define OFF_END (OFF_DON + 4UL * 16 * NSLOT)

#define SMEM_BYTES 106496  // GRU1: 96KB weights + 8KB cross-wave partials

struct Params {
  const float* states;
  const float *Wd1, *bd1, *Wd2, *bd2, *Wm, *bm, *Ws, *bs;
  const float *Wx0, *Wh0, *bx0, *bh0, *Wx1, *Wh1, *bx1, *bh1;
  char* ws;
  float* out;
};

__device__ __forceinline__ unsigned short f2bf(float f) {
  unsigned x = __float_as_uint(f);
  return (unsigned short)((x + 0x7fffu + ((x >> 16) & 1u)) >> 16);
}

// Coherent poll: sc0sc1 load bypasses L1/L2, reads the MALL. Proven (r6 barrier).
__device__ __forceinline__ unsigned cpoll(const unsigned* p) {
  unsigned r;
  asm volatile("global_load_dword %0, %1, off sc0 sc1\n\ts_waitcnt vmcnt(0)"
               : "=v"(r)
               : "v"(p)
               : "memory");
  return r;
}
// Coherent 16B data load (same path as cpoll, wider). No per-load wait:
// batch-issue then vwait0().
__device__ __forceinline__ bf16x8 cload16(const void* p) {
  bf16x8 r;
  asm volatile("global_load_dwordx4 %0, %1, off sc0 sc1" : "=v"(r) : "v"(p));
  return r;
}
__device__ __forceinline__ void vwait0() {
  asm volatile("s_waitcnt vmcnt(0)" ::: "memory");
  __builtin_amdgcn_sched_barrier(0);  // rule #18: pin MFMAs below the wait
}

// ---------------- prep kernel: zero state, bf16-convert & tile weights ----------------
__device__ void prep_gate(const float* src, unsigned short* d, size_t t0, size_t nt) {
  const size_t n = 32UL * 3 * 64 * 128;  // [cg][g][k8][cl][e], src [512][1536]
  for (size_t i = t0; i < n; i += nt) {
    int e = (int)(i & 7), cl = (int)((i >> 3) & 15), k8 = (int)((i >> 7) & 63);
    int g = (int)((i >> 13) % 3), cg = (int)(i / 24576);
    int k = k8 * 8 + e, nn = g * 512 + cg * 16 + cl;
    d[i] = f2bf(src[(size_t)k * 1536 + nn]);
  }
}
__device__ void prep_sq(const float* src, unsigned short* d, size_t t0, size_t nt) {
  const size_t n = 32UL * 64 * 128;  // [cg][k8][cl][e], src [512][512]
  for (size_t i = t0; i < n; i += nt) {
    int e = (int)(i & 7), cl = (int)((i >> 3) & 15), k8 = (int)((i >> 7) & 63);
    int cg = (int)(i >> 13);
    int k = k8 * 8 + e, nn = cg * 16 + cl;
    d[i] = f2bf(src[(size_t)k * 512 + nn]);
  }
}
__device__ void prep_head(const float* src, unsigned short* d, size_t t0, size_t nt) {
  const size_t n = 2UL * 64 * 128;  // [hc][k8][cl][e], src [512][22]
  for (size_t i = t0; i < n; i += nt) {
    int e = (int)(i & 7), cl = (int)((i >> 3) & 15), k8 = (int)((i >> 7) & 63);
    int hc = (int)(i >> 13);
    int k = k8 * 8 + e, nn = hc * 16 + cl;
    d[i] = (nn < Y_) ? f2bf(src[(size_t)k * Y_ + nn]) : (unsigned short)0;
  }
}

extern "C" __global__ void rnn_prep(Params p) {
  char* ws = p.ws;
  size_t t0 = (size_t)blockIdx.x * blockDim.x + threadIdx.x;
  size_t nt = (size_t)gridDim.x * blockDim.x;
  // zero all mutable state (h/d rings, nll, all barrier counters)
  {
    unsigned* z = (unsigned*)(ws + OFF_H0B);
    size_t n = (OFF_END - OFF_H0B) / 4;
    for (size_t i = t0; i < n; i += nt) z[i] = 0u;
  }
  // y -> bf16, K padded to 32
  {
    unsigned short* yb = (unsigned short*)(ws + OFF_YBF);
    size_t n = (size_t)T_ * B_ * 32;
    for (size_t i = t0; i < n; i += nt) {
      int k = (int)(i & 31);
      size_t tb = i >> 5;
      float v = (k < Y_) ? p.states[tb * Y_ + k] : 0.f;
      yb[i] = f2bf(v);
    }
  }
  prep_gate(p.Wh0, (unsigned short*)(ws + OFF_WH0), t0, nt);
  prep_gate(p.Wx1, (unsigned short*)(ws + OFF_WX1), t0, nt);
  prep_gate(p.Wh1, (unsigned short*)(ws + OFF_WH1), t0, nt);
  {  // Wx0 [22][1536] -> [cg][g][k8(4)][16][8], zero-padded K
    unsigned short* d = (unsigned short*)(ws + OFF_WX0);
    size_t n = 32UL * 3 * 4 * 128;
    for (size_t i = t0; i < n; i += nt) {
      int e = (int)(i & 7), cl = (int)((i >> 3) & 15), k8 = (int)((i >> 7) & 3);
      int g = (int)((i >> 9) % 3), cg = (int)(i / 1536);
      int k = k8 * 8 + e, nn = g * 512 + cg * 16 + cl;
      d[i] = (k < Y_) ? f2bf(p.Wx0[(size_t)k * 1536 + nn]) : (unsigned short)0;
    }
  }
  prep_sq(p.Wd1, (unsigned short*)(ws + OFF_WD1), t0, nt);
  prep_sq(p.Wd2, (unsigned short*)(ws + OFF_WD2), t0, nt);
  prep_head(p.Wm, (unsigned short*)(ws + OFF_WM), t0, nt);
  prep_head(p.Ws, (unsigned short*)(ws + OFF_WS2), t0, nt);
}

// ---------------- main persistent kernel ----------------
__device__ __forceinline__ void ldscpy(char* dst, const char* src, int bytes) {
  f32x4* d = (f32x4*)dst;
  const f32x4* s = (const f32x4*)src;
  int n = bytes >> 4;
  for (int i = threadIdx.x; i < n; i += 256) d[i] = s[i];
}

// Elected-fence grid barrier. Semantics identical to r6's proven protocol, but
// the L2 writeback/invalidate (__threadfence) runs ONCE per XCD (last arriver)
// instead of once per WG. Consumers read cross-WG data with sc0sc1 loads, so
// no per-CU acquire is needed. Polls are sc0sc1 (proven coherent, no inv).
__device__ __forceinline__ void gbar(char* ws, int s, unsigned xcd,
                                     unsigned myTotal, unsigned nxcd) {
  __syncthreads();  // drains all waves' vmcnt: block's stores are in local L2
  if (threadIdx.x == 0) {
    unsigned* arr = (unsigned*)(ws + OFF_ARR) + (size_t)xcd * NSLOT + s;
    unsigned* don = (unsigned*)(ws + OFF_DON) + (size_t)xcd * NSLOT + s;
    unsigned* root = (unsigned*)(ws + OFF_ROOT) + (size_t)s * 16;
    unsigned old = atomicAdd(arr, 1u);
    if (old == myTotal - 1u) {
      // last WG on this XCD: all local stores are in this L2 -> flush once
      __threadfence();  // wbl2(+inv): this XCD's L2 -> MALL (proven codegen)
      atomicAdd(root, 1u);
      while (cpoll(root) < nxcd) __builtin_amdgcn_s_sleep(1);
      atomicAdd(don, 1u);
    } else {
      while (cpoll(don) == 0u) __builtin_amdgcn_s_sleep(1);
    }
  }
  __syncthreads();
}

extern "C" __global__ void __launch_bounds__(256) rnn_main(Params p) {
  extern __shared__ char smem[];
  char* ws = p.ws;
  unsigned short* h0b = (unsigned short*)(ws + OFF_H0B);
  unsigned short* h1b = (unsigned short*)(ws + OFF_H1B);
  unsigned short* d1b = (unsigned short*)(ws + OFF_D1);
  unsigned short* d2b = (unsigned short*)(ws + OFF_D2);
  const unsigned short* ybf = (const unsigned short*)(ws + OFF_YBF);

  const int bid = blockIdx.x, tid = threadIdx.x;
  const int wv = tid >> 6, lane = tid & 63;
  const int l16 = lane & 15, lq = lane >> 4;

  // ---- physical XCD id (wave-uniform) ----
  unsigned xcd;
  asm volatile("s_getreg_b32 %0, hwreg(HW_REG_XCC_ID, 0, 4)" : "=s"(xcd));
  xcd &= 15u;

  // ---- prologue: stage this WG's weight columns into LDS (once) ----
  if (bid < 128) {  // GRU1
    int cg = bid & 31;
    ldscpy(smem, ws + OFF_WX1 + (size_t)cg * 49152, 49152);
    ldscpy(smem + 49152, ws + OFF_WH1 + (size_t)cg * 49152, 49152);
  } else if (bid < 192) {  // GRU0
    int cg = (bid - 128) & 31;
    ldscpy(smem, ws + OFF_WH0 + (size_t)cg * 49152, 49152);
    ldscpy(smem + 49152, ws + OFF_WX0 + (size_t)cg * 3072, 3072);
  } else if (bid < 224) {  // D1 (+heads on first 8)
    int cg = bid - 192;
    ldscpy(smem, ws + OFF_WD1 + (size_t)cg * 16384, 16384);
    if (cg < 8) {
      int hc = cg & 1;
      ldscpy(smem + 16384, ws + OFF_WM + (size_t)hc * 16384, 16384);
      ldscpy(smem + 32768, ws + OFF_WS2 + (size_t)hc * 16384, 16384);
    }
  } else {  // D2
    int cg = bid - 224;
    ldscpy(smem, ws + OFF_WD2 + (size_t)cg * 16384, 16384);
  }

  // ---- init: discover per-XCD WG counts (counts read via coherent polls) ----
  unsigned myTotal = 1u, nxcd = 1u;
  if (tid == 0) atomicAdd((unsigned*)(ws + OFF_XCDC) + xcd, 1u);
  __syncthreads();
  if (tid == 0) {
    unsigned* initc = (unsigned*)(ws + OFF_INITC);
    atomicAdd(initc, 1u);
    while (cpoll(initc) < NWG) __builtin_amdgcn_s_sleep(1);
    nxcd = 0u;
    for (int i = 0; i < 16; ++i) nxcd += (cpoll((unsigned*)(ws + OFF_XCDC) + i) != 0u);
    myTotal = cpoll((unsigned*)(ws + OFF_XCDC) + xcd);
  }
  __syncthreads();

  // ---- hoisted per-thread constants + register-resident fp32 h state ----
  f32x4 hreg = {0.f, 0.f, 0.f, 0.f};
  float cA = 0.f, cB = 0.f, cC = 0.f, cD = 0.f, cM = 0.f, cS = 0.f;
  if (bid < 128) {
    const int cg = bid & 31, kh = wv & 1;
    const int j = cg * 16 + l16;
    if (kh == 0) {
      cA = p.bx1[j] + p.bh1[j];
      cB = p.bx1[512 + j] + p.bh1[512 + j];
      cC = p.bx1[1024 + j];
      cD = p.bh1[1024 + j];
    }
  } else if (bid < 192) {
    const int cg = (bid - 128) & 31;
    const int j = cg * 16 + l16;
    cA = p.bx0[j] + p.bh0[j];
    cB = p.bx0[512 + j] + p.bh0[512 + j];
    cC = p.bx0[1024 + j];
    cD = p.bh0[1024 + j];
  } else if (bid < 224) {
    const int cg = bid - 192;
    cA = p.bd1[cg * 16 + l16];
    if (cg < 8 && wv < 2) {
      const int col = (cg & 1) * 16 + l16;
      cM = (col < Y_) ? p.bm[col] : 0.f;
      cS = (col < Y_) ? p.bs[col] : 0.f;
    }
  } else {
    cA = p.bd2[(bid - 224) * 16 + l16];
  }

  for (int s = 0; s < NSLOT; ++s) {
    if (bid < 128) {
      // ========== GRU1: h1(s-1) = GRUcell(h0(s-1), h1(s-2)) ==========
      const int ms = bid >> 5;
      const int mt = wv >> 1, kh = wv & 1;  // 2 waves per 16x16 M-tile, K halved
      float* part = (float*)(smem + 98304);
      const bool act = (s >= 1 && s <= T_);
      const int m0 = 32 * ms + 16 * mt;
      const int j = (bid & 31) * 16 + l16;
      f32x4 aR = {0.f, 0.f, 0.f, 0.f}, aZ = aR, aXN = aR, aHN = aR;
      if (act) {
        const unsigned short* A1 = h0b + ((s - 1) & 1) * 65536;
        const unsigned short* A2 = h1b + ((s - 2) & 1) * 65536;
        const int ab = (m0 + l16) * 512 + kh * 256 + 8 * lq;
        bf16x8 a1[8], a2[8];
#pragma unroll
        for (int kk = 0; kk < 8; ++kk) {
          a1[kk] = cload16(A1 + ab + kk * 32);
          a2[kk] = cload16(A2 + ab + kk * 32);
        }
        if (kh == 0) {
          aR = f32x4{cA, cA, cA, cA};
          aZ = f32x4{cB, cB, cB, cB};
          aXN = f32x4{cC, cC, cC, cC};
          aHN = f32x4{cD, cD, cD, cD};
        }
        const unsigned short* wx = (const unsigned short*)smem;
        const unsigned short* wh = wx + 24576;
        vwait0();
#pragma unroll
        for (int kk = 0; kk < 8; ++kk) {
          int bo = ((kh * 8 + kk) * 4 + lq) * 128 + l16 * 8;
          aR = MFMA(a1[kk], *(const bf16x8*)(wx + bo), aR);
          aZ = MFMA(a1[kk], *(const bf16x8*)(wx + 8192 + bo), aZ);
          aXN = MFMA(a1[kk], *(const bf16x8*)(wx + 16384 + bo), aXN);
          aR = MFMA(a2[kk], *(const bf16x8*)(wh + bo), aR);
          aZ = MFMA(a2[kk], *(const bf16x8*)(wh + 8192 + bo), aZ);
          aHN = MFMA(a2[kk], *(const bf16x8*)(wh + 16384 + bo), aHN);
        }
        if (kh == 1) {
          float* q = part + (mt * 64 + lane) * 16;
          *(f32x4*)(q + 0) = aR;
          *(f32x4*)(q + 4) = aZ;
          *(f32x4*)(q + 8) = aXN;
          *(f32x4*)(q + 12) = aHN;
        }
      }
      __syncthreads();
      if (act && kh == 0) {
        const float* q = part + (mt * 64 + lane) * 16;
        aR += *(const f32x4*)(q + 0);
        aZ += *(const f32x4*)(q + 4);
        aXN += *(const f32x4*)(q + 8);
        aHN += *(const f32x4*)(q + 12);
        unsigned short* hbn = h1b + ((s - 1) & 1) * 65536;
#pragma unroll
        for (int i = 0; i < 4; ++i) {
          int row = m0 + lq * 4 + i;
          float r = 1.f / (1.f + __expf(-aR[i]));
          float z = 1.f / (1.f + __expf(-aZ[i]));
          float n = tanhf(aXN[i] + r * aHN[i]);
          float hv = (1.f - z) * n + z * hreg[i];
          hreg[i] = hv;
          hbn[row * 512 + j] = f2bf(hv);  // plain store; flushed by elected wbl2
        }
      }
    } else if (bid < 192) {
      // ========== GRU0: h0(s) = GRUcell(y_s, h0(s-1)) ==========
      const int idx = bid - 128, ms = idx >> 5, cg = idx & 31;
      if (s < T_) {
        const unsigned short* A = h0b + ((s - 1) & 1) * 65536;
        const int m0 = 64 * ms + 16 * wv;
        const int j = cg * 16 + l16;
        const int ab = (m0 + l16) * 512 + 8 * lq;
        bf16x8 a[16];
#pragma unroll
        for (int kk = 0; kk < 16; ++kk) a[kk] = cload16(A + ab + kk * 32);
        const unsigned short* wh = (const unsigned short*)smem;
        const unsigned short* wx = wh + 24576;
        f32x4 aR = {cA, cA, cA, cA}, aZ = {cB, cB, cB, cB};
        f32x4 aN = {cC, cC, cC, cC}, aH = {cD, cD, cD, cD};
        {  // x-part under the in-flight coherent loads (y is read-only, plain)
          bf16x8 ya = *(const bf16x8*)(ybf + (size_t)s * (128 * 32) + (m0 + l16) * 32 + 8 * lq);
          int bo = lq * 128 + l16 * 8;
          aR = MFMA(ya, *(const bf16x8*)(wx + bo), aR);
          aZ = MFMA(ya, *(const bf16x8*)(wx + 512 + bo), aZ);
          aN = MFMA(ya, *(const bf16x8*)(wx + 1024 + bo), aN);
        }
        vwait0();
#pragma unroll
        for (int kk = 0; kk < 16; ++kk) {
          int bo = (kk * 4 + lq) * 128 + l16 * 8;
          aR = MFMA(a[kk], *(const bf16x8*)(wh + bo), aR);
          aZ = MFMA(a[kk], *(const bf16x8*)(wh + 8192 + bo), aZ);
          aH = MFMA(a[kk], *(const bf16x8*)(wh + 16384 + bo), aH);
        }
        unsigned short* hbn = h0b + (s & 1) * 65536;
#pragma unroll
        for (int i = 0; i < 4; ++i) {
          int row = m0 + lq * 4 + i;
          float r = 1.f / (1.f + __expf(-aR[i]));
          float z = 1.f / (1.f + __expf(-aZ[i]));
          float n = tanhf(aN[i] + r * aH[i]);
          float hv = (1.f - z) * n + z * hreg[i];
          hreg[i] = hv;
          hbn[row * 512 + j] = f2bf(hv);
        }
      }
    } else if (bid < 224) {
      // ========== D1: d1(s-1) = relu(h1(s-2) @ Wd1 + bd1)  (+ heads/NLL) ==========
      const int cg = bid - 192;
      const bool actH = (cg < 8 && wv < 2 && s >= 3);
      bf16x8 hd[16];
      int m0h = 0;
      if (actH) {  // issue head loads early; they retire under D1 compute
        const unsigned short* Ah = d2b + ((s - 3) & 1) * 65536;
        m0h = 32 * (cg >> 1) + 16 * wv;
        const int abh = (m0h + l16) * 512 + 8 * lq;
#pragma unroll
        for (int kk = 0; kk < 16; ++kk) hd[kk] = cload16(Ah + abh + kk * 32);
      }
      if (s >= 1 && s <= T_) {
        const unsigned short* A = h1b + ((s - 2) & 1) * 65536;
        unsigned short* dst = d1b + ((s - 1) & 1) * 65536;
        const unsigned short* wd = (const unsigned short*)smem;
        const int j = cg * 16 + l16;
#pragma unroll
        for (int half = 0; half < 2; ++half) {
          int m0 = (wv * 2 + half) * 16;
          int ab = (m0 + l16) * 512 + 8 * lq;
          bf16x8 a[16];
#pragma unroll
          for (int kk = 0; kk < 16; ++kk) a[kk] = cload16(A + ab + kk * 32);
          f32x4 acc = {cA, cA, cA, cA};
          vwait0();
#pragma unroll
          for (int kk = 0; kk < 16; ++kk) {
            int bo = (kk * 4 + lq) * 128 + l16 * 8;
            acc = MFMA(a[kk], *(const bf16x8*)(wd + bo), acc);
          }
#pragma unroll
          for (int i = 0; i < 4; ++i) {
            int row = m0 + lq * 4 + i;
            float v = acc[i];
            dst[row * 512 + j] = f2bf(v > 0.f ? v : 0.f);
          }
        }
      }
      if (actH) {
        const int tau = s - 3;
        const int hc = cg & 1;
        const unsigned short* wm = (const unsigned short*)(smem + 16384);
        const unsigned short* wst = (const unsigned short*)(smem + 32768);
        const int col = hc * 16 + l16;
        f32x4 aM = {cM, cM, cM, cM}, aS = {cS, cS, cS, cS};
        vwait0();
#pragma unroll
        for (int kk = 0; kk < 16; ++kk) {
          int bo = (kk * 4 + lq) * 128 + l16 * 8;
          aM = MFMA(hd[kk], *(const bf16x8*)(wm + bo), aM);
          aS = MFMA(hd[kk], *(const bf16x8*)(wst + bo), aS);
        }
        float lsum = 0.f;
        if (col < Y_) {
#pragma unroll
          for (int i = 0; i < 4; ++i) {
            int row = m0h + lq * 4 + i;
            float sp = aS[i];
            float sd = (sp > 20.f) ? sp : log1pf(__expf(sp));
            float yv = p.states[((size_t)tau * B_ + row) * Y_ + col];
            float tt = (yv - aM[i]) / sd;
            lsum += 0.5f * tt * tt + __logf(sd) + LOG_SQRT_2PI;
          }
        }
#pragma unroll
        for (int off = 32; off > 0; off >>= 1) lsum += __shfl_down(lsum, off);
        if (lane == 0) atomicAdd((float*)(ws + OFF_NLL), lsum);
      }
    } else {
      // ========== D2: d2(s-2) = relu(d1(s-2) @ Wd2 + bd2) ==========
      const int cg = bid - 224;
      if (s >= 2 && s <= T_ + 1) {
        const unsigned short* A = d1b + ((s - 2) & 1) * 65536;
        unsigned short* dst = d2b + ((s - 2) & 1) * 65536;
        const unsigned short* wd = (const unsigned short*)smem;
        const int j = cg * 16 + l16;
#pragma unroll
        for (int half = 0; half < 2; ++half) {
          int m0 = (wv * 2 + half) * 16;
          int ab = (m0 + l16) * 512 + 8 * lq;
          bf16x8 a[16];
#pragma unroll
          for (int kk = 0; kk < 16; ++kk) a[kk] = cload16(A + ab + kk * 32);
          f32x4 acc = {cA, cA, cA, cA};
          vwait0();
#pragma unroll
          for (int kk = 0; kk < 16; ++kk) {
            int bo = (kk * 4 + lq) * 128 + l16 * 8;
            acc = MFMA(a[kk], *(const bf16x8*)(wd + bo), acc);
          }
#pragma unroll
          for (int i = 0; i < 4; ++i) {
            int row = m0 + lq * 4 + i;
            float v = acc[i];
            dst[row * 512 + j] = f2bf(v > 0.f ? v : 0.f);
          }
        }
      }
    }
    gbar(ws, s, xcd, myTotal, nxcd);
  }

  if (bid == 0 && tid == 0) {
    // NLL was accumulated with device-scope atomics (MALL); read coherently.
    unsigned u = cpoll((const unsigned*)(ws + OFF_NLL));
    p.out[0] = __uint_as_float(u);
  }
}

// ---------------- host launcher ----------------
extern "C" void kernel_launch(void* const* d_in, const int* in_sizes, int n_in,
                              void* d_out, int out_size, void* d_ws, size_t ws_size,
                              hipStream_t stream) {
  if (ws_size < OFF_END) return;  // insufficient scratch -> visible failure
  Params p;
  p.states = (const float*)d_in[0];
  p.Wd1 = (const float*)d_in[1];
  p.bd1 = (const float*)d_in[2];
  p.Wd2 = (const float*)d_in[3];
  p.bd2 = (const float*)d_in[4];
  p.Wm = (const float*)d_in[5];
  p.bm = (const float*)d_in[6];
  p.Ws = (const float*)d_in[7];
  p.bs = (const float*)d_in[8];
  p.Wx0 = (const float*)d_in[9];
  p.Wh0 = (const float*)d_in[10];
  p.bx0 = (const float*)d_in[11];
  p.bh0 = (const float*)d_in[12];
  p.Wx1 = (const float*)d_in[13];
  p.Wh1 = (const float*)d_in[14];
  p.bx1 = (const float*)d_in[15];
  p.bh1 = (const float*)d_in[16];
  p.ws = (char*)d_ws;
  p.out = (float*)d_out;

  hipLaunchKernelGGL(rnn_prep, dim3(512), dim3(256), 0, stream, p);

  hipFuncSetAttribute((const void*)rnn_main, hipFuncAttributeMaxDynamicSharedMemorySize,
                      SMEM_BYTES);
  void* args[] = {&p};
  hipError_t rc = hipLaunchCooperativeKernel((const void*)rnn_main, dim3(NWG), dim3(256),
                                             args, SMEM_BYTES, stream);
  if (rc != hipSuccess) {
    // co-residency is guaranteed at 1 WG/CU with 256 WGs; spin barrier is safe
    hipLaunchKernelGGL(rnn_main, dim3(NWG), dim3(256), SMEM_BYTES, stream, p);
  }
}